// Round 1
// baseline (194.233 us; speedup 1.0000x reference)
//
#include <hip/hip_runtime.h>

#define K_NEIGH 32
#define D_FEAT  128

// One wave (64 lanes) per batch element.
// Lane l owns feature dims [4*(l&31), 4*(l&31)+4) as a float4.
// Lower half-wave (lanes 0..31) processes even k, upper half odd k:
// 16 fully-unrolled iterations cover K=32 neighbors with independent,
// fully-coalesced 512B-per-half-wave float4 loads.
__global__ __launch_bounds__(256, 4) void intra_agg_kernel(
    const float* __restrict__ features,
    const int*   __restrict__ nodes,
    const int*   __restrict__ neighs,
    const int*   __restrict__ num_sample_p,
    float*       __restrict__ out,
    int batch)
{
    const int gtid = blockIdx.x * blockDim.x + threadIdx.x;
    const int b    = gtid >> 6;           // one wave per batch element
    const int lane = threadIdx.x & 63;
    if (b >= batch) return;               // wave-uniform (batch % 4 == 0 anyway)

    const int ns   = *num_sample_p;
    const int half = lane >> 5;           // 0: even k, 1: odd k
    const int l32  = lane & 31;

    // Center row fragment (both halves hold a full copy across their 32 lanes).
    const int   cnode = nodes[b];
    const float4 c = ((const float4*)(features + (size_t)cnode * D_FEAT))[l32];

    // Lane l holds neighbor index l&31 (two coalesced copies per wave).
    const int idx_l = neighs[b * K_NEIGH + l32];

    // ||center||^2 via 5-step butterfly within each half-wave.
    float c2 = c.x*c.x + c.y*c.y + c.z*c.z + c.w*c.w;
    #pragma unroll
    for (int m = 16; m >= 1; m >>= 1) c2 += __shfl_xor(c2, m);
    const float cn = sqrtf(c2);

    float  sim = 0.0f;        // will hold sim_{l32} on every lane
    float4 rowreg[16];        // this lane's quarter of each of its 16 k-rows

    #pragma unroll
    for (int kk = 0; kk < 16; ++kk) {
        const int k    = 2 * kk + half;
        const int nidx = __shfl(idx_l, k, 32);   // within-half broadcast of idx_k
        const float4 r = ((const float4*)(features + (size_t)nidx * D_FEAT))[l32];
        rowreg[kk] = r;

        float dt = c.x*r.x + c.y*r.y + c.z*r.z + c.w*r.w;
        float n2 = r.x*r.x + r.y*r.y + r.z*r.z + r.w*r.w;
        #pragma unroll
        for (int m = 16; m >= 1; m >>= 1) {
            dt += __shfl_xor(dt, m);
            n2 += __shfl_xor(n2, m);
        }
        // Exchange totals across halves so every lane sees both parities.
        const float dt_o = __shfl_xor(dt, 32);
        const float n2_o = __shfl_xor(n2, 32);
        const float dt_e = half ? dt_o : dt;
        const float n2_e = half ? n2_o : n2;
        const float dt_d = half ? dt   : dt_o;
        const float n2_d = half ? n2   : n2_o;
        // Deposit sim_k into lane l32 == k (in both halves identically).
        if (l32 == 2 * kk)     sim = dt_e / (cn * sqrtf(n2_e));
        if (l32 == 2 * kk + 1) sim = dt_d / (cn * sqrtf(n2_d));
    }

    // Stable top-ns selection: rank = #{j: s_j > s_k} + #{j<k: s_j == s_k}.
    int rank = 0;
    #pragma unroll
    for (int j = 0; j < 32; ++j) {
        const float sj = __shfl(sim, j, 32);
        rank += (sj > sim || (sj == sim && j < l32)) ? 1 : 0;
    }
    const bool sel = (rank < ns);
    const unsigned long long bal = __ballot(sel);
    const unsigned mask = (unsigned)(bal & 0xffffffffull);  // bit k = select k

    // Predicated accumulate of this lane's stored quarter-rows (no divergence).
    float4 acc = make_float4(0.f, 0.f, 0.f, 0.f);
    #pragma unroll
    for (int kk = 0; kk < 16; ++kk) {
        const int   k = 2 * kk + half;
        const float s = (float)((mask >> k) & 1u);
        acc.x = fmaf(rowreg[kk].x, s, acc.x);
        acc.y = fmaf(rowreg[kk].y, s, acc.y);
        acc.z = fmaf(rowreg[kk].z, s, acc.z);
        acc.w = fmaf(rowreg[kk].w, s, acc.w);
    }
    // Combine even-k (lower half) and odd-k (upper half) partial sums.
    acc.x += __shfl_xor(acc.x, 32);
    acc.y += __shfl_xor(acc.y, 32);
    acc.z += __shfl_xor(acc.z, 32);
    acc.w += __shfl_xor(acc.w, 32);

    if (half == 0) {
        const float nsf = (float)ns;
        float4 o;
        o.x = fmaxf(acc.x / nsf, 0.0f);
        o.y = fmaxf(acc.y / nsf, 0.0f);
        o.z = fmaxf(acc.z / nsf, 0.0f);
        o.w = fmaxf(acc.w / nsf, 0.0f);
        ((float4*)(out + (size_t)b * D_FEAT))[l32] = o;
    }
}

extern "C" void kernel_launch(void* const* d_in, const int* in_sizes, int n_in,
                              void* d_out, int out_size, void* d_ws, size_t ws_size,
                              hipStream_t stream) {
    const float* features = (const float*)d_in[0];
    const int*   nodes    = (const int*)d_in[1];
    const int*   neighs   = (const int*)d_in[2];
    const int*   ns       = (const int*)d_in[3];
    float*       out      = (float*)d_out;

    const int batch  = in_sizes[1];           // 32768
    const int blocks = (batch + 3) / 4;       // 4 waves (batch elems) per 256-thr block

    intra_agg_kernel<<<blocks, 256, 0, stream>>>(features, nodes, neighs, ns, out, batch);
}